// Round 3
// baseline (271.105 us; speedup 1.0000x reference)
//
#include <hip/hip_runtime.h>
#include <hip/hip_bf16.h>

#define TWO_PI_F 6.283185307179586f
#define EPS_F 1e-6f
#define BATCH 32

// Replace non-finite by 0 (bit test so fast-math can't fold it away).
__device__ __forceinline__ float sane(float x) {
    return ((__float_as_uint(x) & 0x7f800000u) == 0x7f800000u) ? 0.f : x;
}

// One fused layer: [apply prev batchnorm] -> gm_convolve -> eval_at_centers ->
// relu_fit (top-KOUT) -> write selected comps + per-(b,lo) abs-integral total.
// Grid: BATCH*LO blocks, 256 threads.
template<int LO, int LI, int ND, int NK, int NCOMP, int KOUT, bool FIRST>
__global__ __launch_bounds__(256) void layer_kernel(
    const float* __restrict__ in_x,            // FIRST: (B,1,64,7) f32
    const float* __restrict__ prev_sel,        // !FIRST: (B,LI,ND,7) f32
    const float* __restrict__ prev_tot,        // !FIRST: (B,LI) f32
    const float* __restrict__ kern,            // (LO,LI,NK,7) f32
    const float* __restrict__ bias,            // (LO,) f32
    float* __restrict__ out_sel,               // (B,LO,KOUT,7) f32
    float* __restrict__ out_tot)               // (B,LO) f32
{
    const int b   = blockIdx.x / LO;
    const int lo  = blockIdx.x % LO;
    const int tid = threadIdx.x;

    __shared__ float  d_w[LI*ND], d_px[LI*ND], d_py[LI*ND];
    __shared__ float4 d_c[LI*ND];
    __shared__ float  k_w[LI*NK], k_px[LI*NK], k_py[LI*NK];
    __shared__ float4 k_c[LI*NK];
    __shared__ float4 eA[NCOMP];   // w, px, py, -0.5*i00
    __shared__ float2 eB[NCOMP];   // -0.5*(i01+i10), -0.5*i11
    __shared__ float4 cC[NCOMP];   // C00,C01,C10,C11
    __shared__ float  w2s[NCOMP], a2s[NCOMP];
    __shared__ float  redv[256];
    __shared__ int    redi[256];
    __shared__ int    selidx[KOUT];
    __shared__ float  dscale[LI];

    // ---- Phase pre: incoming batchnorm + stage data/kernel into LDS
    if constexpr (FIRST) {
        // per_gaussian=True batchnorm on raw input (LI==1, ND==64)
        if (tid < ND) {
            const float* s = in_x + (size_t)(b*ND + tid)*7;
            const float w  = sane(s[0]);
            const float c0 = sane(s[3]), c1 = sane(s[4]), c2 = sane(s[5]), c3 = sane(s[6]);
            d_w[tid] = w; d_px[tid] = sane(s[1]); d_py[tid] = sane(s[2]);
            d_c[tid] = make_float4(c0, c1, c2, c3);
            const float det = c0*c3 - c1*c2;
            redv[tid] = sane(fabsf(w) * TWO_PI_F * sqrtf(fmaxf(det, EPS_F)));
        }
        __syncthreads();
        if (tid == 0) {
            float s = 0.f;
            for (int i = 0; i < ND; ++i) s += redv[i];
            dscale[0] = 1.f / (s + EPS_F);
        }
        __syncthreads();
        if (tid < ND) d_w[tid] = sane(d_w[tid] * dscale[0]);
    } else {
        // per_gaussian=False batchnorm: per input channel li, mean over batch
        if (tid < LI) {
            float s = 0.f;
            for (int bb = 0; bb < BATCH; ++bb) s += prev_tot[bb*LI + tid];
            dscale[tid] = 1.f / (s / (float)BATCH + EPS_F);
        }
        __syncthreads();
        for (int j = tid; j < LI*ND; j += 256) {
            const int li = j / ND;
            const float* s = prev_sel + (size_t)(b*LI*ND + j)*7;
            d_w[j]  = sane(s[0] * dscale[li]);
            d_px[j] = s[1]; d_py[j] = s[2];
            d_c[j]  = make_float4(s[3], s[4], s[5], s[6]);
        }
    }
    for (int j = tid; j < LI*NK; j += 256) {
        const float* s = kern + (size_t)(lo*LI*NK + j)*7;
        k_w[j]  = sane(s[0]);
        k_px[j] = sane(s[1]); k_py[j] = sane(s[2]);
        k_c[j]  = make_float4(sane(s[3]), sane(s[4]), sane(s[5]), sane(s[6]));
    }
    __syncthreads();

    // ---- Phase A: gm_convolve -> NCOMP components in LDS
    // Component flattening matches reference reshape: (li, nd, nk), nk fastest.
    for (int j = tid; j < NCOMP; j += 256) {
        const int li = j / (ND*NK);
        const int r  = j % (ND*NK);
        const int nd = r / NK, nk = r % NK;
        const int di = li*ND + nd, ki = li*NK + nk;
        const float4 dc = d_c[di], kc = k_c[ki];
        const float c0 = dc.x + kc.x, c1 = dc.y + kc.y, c2 = dc.z + kc.z, c3 = dc.w + kc.w;
        const float dd = dc.x*dc.w - dc.y*dc.z;
        const float dk = kc.x*kc.w - kc.y*kc.z;
        const float ds = c0*c3 - c1*c2;
        const float w  = sane(d_w[di]*k_w[ki]*TWO_PI_F*sqrtf(fmaxf(dd*dk, 0.f) / fmaxf(ds, EPS_F)));
        const float px = sane(d_px[di] + k_px[ki]);
        const float py = sane(d_py[di] + k_py[ki]);
        const float inv = 1.f / ds;   // reference inv2 uses the raw determinant
        const float i00 = sane(c3*inv), i01s = sane(-(c1 + c2)*inv), i11 = sane(c0*inv);
        eA[j] = make_float4(w, px, py, -0.5f*i00);
        eB[j] = make_float2(-0.5f*i01s, -0.5f*i11);
        cC[j] = make_float4(sane(c0), sane(c1), sane(c2), sane(c3));
    }
    __syncthreads();

    // ---- Phase B: eval_at_centers + relu scaling
    constexpr int KP = (NCOMP + 255) / 256;
    float acc[KP], kx[KP], ky[KP];
    #pragma unroll
    for (int i = 0; i < KP; ++i) {
        const int k = tid + i*256;
        kx[i] = 0.f; ky[i] = 0.f; acc[i] = 0.f;
        if (k < NCOMP) { const float4 a = eA[k]; kx[i] = a.y; ky[i] = a.z; }
    }
    for (int n = 0; n < NCOMP; ++n) {
        const float4 a = eA[n];
        const float2 e = eB[n];
        #pragma unroll
        for (int i = 0; i < KP; ++i) {
            const float dx = kx[i] - a.y;
            const float dy = ky[i] - a.z;
            const float md = fminf(a.w*dx*dx + e.x*dx*dy + e.y*dy*dy, 0.f);
            acc[i] += a.x * __expf(md);
        }
    }
    {
        const float bi = sane(bias[lo]);
        #pragma unroll
        for (int i = 0; i < KP; ++i) {
            const int k = tid + i*256;
            if (k < NCOMP) {
                const float v = acc[i] + bi;
                const float sc = fmaxf(v, 0.f) / (fabsf(v) + EPS_F);
                const float ww = sane(eA[k].x * sc);
                w2s[k] = ww; a2s[k] = fabsf(ww);
            }
        }
    }
    __syncthreads();

    // ---- Phase C: top-KOUT by |w2| (iterative argmax, lowest index on ties —
    // matches jax.lax.top_k's stable descending order)
    for (int it = 0; it < KOUT; ++it) {
        float bv = -1.f; int bidx = 0x7fffffff;
        for (int k = tid; k < NCOMP; k += 256) {
            const float vv = a2s[k];
            if (vv > bv || (vv == bv && k < bidx)) { bv = vv; bidx = k; }
        }
        redv[tid] = bv; redi[tid] = bidx;
        __syncthreads();
        for (int off = 128; off > 0; off >>= 1) {
            if (tid < off) {
                const float ov = redv[tid+off]; const int oi = redi[tid+off];
                if (ov > redv[tid] || (ov == redv[tid] && oi < redi[tid])) {
                    redv[tid] = ov; redi[tid] = oi;
                }
            }
            __syncthreads();
        }
        if (tid == 0) {
            int ksel = redi[0];
            if (ksel < 0 || ksel >= NCOMP) ksel = 0;   // guard (no-op normally)
            selidx[it] = ksel;
            a2s[ksel] = -2.f;
        }
        __syncthreads();
    }

    // ---- Phase D: write selected comps + per-(b,lo) abs-integral total
    if (tid < KOUT) {
        const int k = selidx[tid];
        const float4 a = eA[k];
        const float4 c = cC[k];
        const float ww = w2s[k];
        float* dst = out_sel + (size_t)((b*LO + lo)*KOUT + tid)*7;
        dst[0] = ww; dst[1] = a.y; dst[2] = a.z;
        dst[3] = c.x; dst[4] = c.y; dst[5] = c.z; dst[6] = c.w;
        const float det = c.x*c.w - c.y*c.z;
        redv[tid] = sane(fabsf(ww) * TWO_PI_F * sqrtf(fmaxf(det, EPS_F)));
    }
    __syncthreads();
    if (tid == 0) {
        float s = 0.f;
        for (int i = 0; i < KOUT; ++i) s += redv[i];
        out_tot[b*LO + lo] = s;
    }
}

// Final: batchnorm3 scale (mean over batch) -> integrate -> log_softmax -> f32
__global__ __launch_bounds__(64) void final_kernel(
    const float* __restrict__ sel3,   // (B,10,5,7)
    const float* __restrict__ tot3,   // (B,10)
    float* __restrict__ out)          // (B,10) f32
{
    const int b = blockIdx.x;
    const int tid = threadIdx.x;
    __shared__ float scale3[10], integ[10], red2[2];
    if (tid < 10) {
        float s = 0.f;
        for (int bb = 0; bb < BATCH; ++bb) s += tot3[bb*10 + tid];
        scale3[tid] = 1.f / (s / (float)BATCH + EPS_F);
    }
    __syncthreads();
    if (tid < 10) {
        float s = 0.f;
        const float* base = sel3 + (size_t)((b*10 + tid)*5)*7;
        for (int kk = 0; kk < 5; ++kk) {
            const float* c = base + kk*7;
            const float det = c[3]*c[6] - c[4]*c[5];
            s += c[0] * scale3[tid] * TWO_PI_F * sqrtf(fmaxf(det, EPS_F));
        }
        integ[tid] = sane(s);
    }
    __syncthreads();
    if (tid == 0) {
        float m = -1e30f;
        for (int l = 0; l < 10; ++l) m = fmaxf(m, integ[l]);
        float ss = 0.f;
        for (int l = 0; l < 10; ++l) ss += __expf(integ[l] - m);
        red2[0] = m; red2[1] = logf(ss);
    }
    __syncthreads();
    if (tid < 10) out[b*10 + tid] = integ[tid] - red2[0] - red2[1];
}

extern "C" void kernel_launch(void* const* d_in, const int* in_sizes, int n_in,
                              void* d_out, int out_size, void* d_ws, size_t ws_size,
                              hipStream_t stream)
{
    const float* in_x = (const float*)d_in[0];
    const float* k1   = (const float*)d_in[1];
    const float* k2   = (const float*)d_in[2];
    const float* k3   = (const float*)d_in[3];
    const float* b1   = (const float*)d_in[4];
    const float* b2   = (const float*)d_in[5];
    const float* b3   = (const float*)d_in[6];
    float* out = (float*)d_out;   // reference output dtype is float32

    float* ws = (float*)d_ws;
    float* sel1 = ws;                  // 32*5*25*7  = 28000 floats
    float* tot1 = ws + 28000;          // 160
    float* sel2 = ws + 28160;          // 32*6*12*7  = 16128
    float* tot2 = ws + 44288;          // 192
    float* sel3 = ws + 44480;          // 32*10*5*7  = 11200
    float* tot3 = ws + 55680;          // 320  (total ~224 KB)

    // Layer 1: (32,1,64) conv (5,1,5) -> 320 comps, keep 25
    layer_kernel<5, 1, 64, 5, 320, 25, true><<<BATCH*5, 256, 0, stream>>>(
        in_x, nullptr, nullptr, k1, b1, sel1, tot1);
    // Layer 2: (32,5,25) conv (6,5,5) -> 625 comps, keep 12
    layer_kernel<6, 5, 25, 5, 625, 12, false><<<BATCH*6, 256, 0, stream>>>(
        nullptr, sel1, tot1, k2, b2, sel2, tot2);
    // Layer 3: (32,6,12) conv (10,6,5) -> 360 comps, keep 5
    layer_kernel<10, 6, 12, 5, 360, 5, false><<<BATCH*10, 256, 0, stream>>>(
        nullptr, sel2, tot2, k3, b3, sel3, tot3);
    // Final: batchnorm + integrate + log_softmax
    final_kernel<<<BATCH, 64, 0, stream>>>(sel3, tot3, out);
}

// Round 4
// 219.007 us; speedup vs baseline: 1.2379x; 1.2379x over previous
//
#include <hip/hip_runtime.h>

#define TWO_PI_F 6.283185307179586f
#define EPS_F 1e-6f
#define BATCH 32
#define NT 1024

// Replace non-finite by 0 (bit test so fast-math can't fold it away).
__device__ __forceinline__ float sane(float x) {
    return ((__float_as_uint(x) & 0x7f800000u) == 0x7f800000u) ? 0.f : x;
}

// One fused layer: [apply prev batchnorm] -> gm_convolve -> eval_at_centers ->
// relu_fit (top-KOUT via rank) -> write selected comps + per-(b,lo) abs-integral.
// Grid: BATCH*LO blocks, NT=1024 threads (16 waves -> 4/SIMD latency hiding).
// Eval parallelization: thread t -> (g = t/KPAD, k = t%KPAD); group g sums the
// n-slice [g*CHUNK, ...); partials reduced through LDS. KPAD is a multiple of
// 64 so groups are wave-aligned (LDS reads of eA[n]/eB[n] stay broadcasts).
template<int LO, int LI, int ND, int NK, int NCOMP, int KOUT, int KPAD, int G, bool FIRST>
__global__ __launch_bounds__(NT) void layer_kernel(
    const float* __restrict__ in_x,            // FIRST: (B,1,64,7) f32
    const float* __restrict__ prev_sel,        // !FIRST: (B,LI,ND,7) f32
    const float* __restrict__ prev_tot,        // !FIRST: (B,LI) f32
    const float* __restrict__ kern,            // (LO,LI,NK,7) f32
    const float* __restrict__ bias,            // (LO,) f32
    float* __restrict__ out_sel,               // (B,LO,KOUT,7) f32
    float* __restrict__ out_tot)               // (B,LO) f32
{
    const int b   = blockIdx.x / LO;
    const int lo  = blockIdx.x % LO;
    const int tid = threadIdx.x;
    const int g   = tid / KPAD;
    const int k   = tid % KPAD;

    __shared__ float  d_w[LI*ND], d_px[LI*ND], d_py[LI*ND];
    __shared__ float4 d_c[LI*ND];
    __shared__ float  k_w[LI*NK], k_px[LI*NK], k_py[LI*NK];
    __shared__ float4 k_c[LI*NK];
    __shared__ float4 eA[NCOMP];   // w, px, py, -0.5*i00
    __shared__ float2 eB[NCOMP];   // -0.5*(i01+i10), -0.5*i11
    __shared__ float4 cC[NCOMP];   // C00,C01,C10,C11
    __shared__ float  w2s[NCOMP], a2s[NCOMP];
    __shared__ float  accbuf[(G > 1) ? KPAD*G : 1];
    __shared__ float  scr[64];     // small reductions
    __shared__ float  selint[32];  // per-selected-slot integral (KOUT <= 25)
    __shared__ float  dscale[LI];

    // ---- Phase pre: incoming batchnorm + stage data/kernel into LDS
    if constexpr (FIRST) {
        // per_gaussian=True batchnorm on raw input (LI==1, ND==64)
        if (tid < ND) {
            const float* s = in_x + (size_t)(b*ND + tid)*7;
            const float w  = sane(s[0]);
            const float c0 = sane(s[3]), c1 = sane(s[4]), c2 = sane(s[5]), c3 = sane(s[6]);
            d_w[tid] = w; d_px[tid] = sane(s[1]); d_py[tid] = sane(s[2]);
            d_c[tid] = make_float4(c0, c1, c2, c3);
            const float det = c0*c3 - c1*c2;
            scr[tid] = sane(fabsf(w) * TWO_PI_F * sqrtf(fmaxf(det, EPS_F)));
        }
        __syncthreads();
        if (tid == 0) {
            float s = 0.f;
            for (int i = 0; i < ND; ++i) s += scr[i];
            dscale[0] = 1.f / (s + EPS_F);
        }
        __syncthreads();
        if (tid < ND) d_w[tid] = sane(d_w[tid] * dscale[0]);
    } else {
        // per_gaussian=False batchnorm: per input channel li, mean over batch
        if (tid < LI) {
            float s = 0.f;
            for (int bb = 0; bb < BATCH; ++bb) s += prev_tot[bb*LI + tid];
            dscale[tid] = 1.f / (s / (float)BATCH + EPS_F);
        }
        __syncthreads();
        if (tid < LI*ND) {
            const int li = tid / ND;
            const float* s = prev_sel + (size_t)(b*LI*ND + tid)*7;
            d_w[tid]  = sane(s[0] * dscale[li]);
            d_px[tid] = s[1]; d_py[tid] = s[2];
            d_c[tid]  = make_float4(s[3], s[4], s[5], s[6]);
        }
    }
    if (tid < LI*NK) {
        const float* s = kern + (size_t)(lo*LI*NK + tid)*7;
        k_w[tid]  = sane(s[0]);
        k_px[tid] = sane(s[1]); k_py[tid] = sane(s[2]);
        k_c[tid]  = make_float4(sane(s[3]), sane(s[4]), sane(s[5]), sane(s[6]));
    }
    __syncthreads();

    // ---- Phase A: gm_convolve -> NCOMP components in LDS
    // Flattening matches reference reshape: (li, nd, nk), nk fastest.
    if (tid < NCOMP) {
        const int li = tid / (ND*NK);
        const int r  = tid % (ND*NK);
        const int nd = r / NK, nk = r % NK;
        const int di = li*ND + nd, ki = li*NK + nk;
        const float4 dc = d_c[di], kc = k_c[ki];
        const float c0 = dc.x + kc.x, c1 = dc.y + kc.y, c2 = dc.z + kc.z, c3 = dc.w + kc.w;
        const float dd = dc.x*dc.w - dc.y*dc.z;
        const float dk = kc.x*kc.w - kc.y*kc.z;
        const float ds = c0*c3 - c1*c2;
        const float w  = sane(d_w[di]*k_w[ki]*TWO_PI_F*sqrtf(fmaxf(dd*dk, 0.f) / fmaxf(ds, EPS_F)));
        const float px = sane(d_px[di] + k_px[ki]);
        const float py = sane(d_py[di] + k_py[ki]);
        const float inv = 1.f / ds;   // reference inv2 uses the raw determinant
        const float i00 = sane(c3*inv), i01s = sane(-(c1 + c2)*inv), i11 = sane(c0*inv);
        eA[tid] = make_float4(w, px, py, -0.5f*i00);
        eB[tid] = make_float2(-0.5f*i01s, -0.5f*i11);
        cC[tid] = make_float4(sane(c0), sane(c1), sane(c2), sane(c3));
    }
    __syncthreads();

    // ---- Phase B: eval_at_centers (group-split over n) + relu scaling
    constexpr int CHUNK = (NCOMP + G - 1) / G;
    float kx = 0.f, ky = 0.f;
    if (k < NCOMP) { const float4 a = eA[k]; kx = a.y; ky = a.z; }
    float acc = 0.f;
    if (g < G) {
        const int n0 = g*CHUNK;
        const int n1 = (n0 + CHUNK < NCOMP) ? (n0 + CHUNK) : NCOMP;
        #pragma unroll 4
        for (int n = n0; n < n1; ++n) {
            const float4 a = eA[n];   // broadcast (all lanes same n)
            const float2 e = eB[n];
            const float dx = kx - a.y;
            const float dy = ky - a.z;
            const float md = dx*(a.w*dx + e.x*dy) + e.y*dy*dy;  // = -0.5*quadform
            acc += a.x * __expf(md);
        }
    }
    if constexpr (G > 1) {
        if (g > 0 && g < G) accbuf[tid] = acc;
        __syncthreads();
        if (g == 0 && k < NCOMP) {
            #pragma unroll
            for (int gg = 1; gg < G; ++gg) acc += accbuf[k + gg*KPAD];
        }
    }
    if (g == 0 && k < NCOMP) {
        const float v  = acc + bias[lo];
        const float sc = fmaxf(v, 0.f) / (fabsf(v) + EPS_F);
        const float ww = sane(eA[k].x * sc);
        w2s[k] = ww; a2s[k] = fabsf(ww);
    }
    __syncthreads();

    // ---- Phase C+D: rank-based top-KOUT (stable descending, == jax.lax.top_k)
    // rank k = #{j : |w2[j]| > |w2[k]|  or  (|w2[j]| == |w2[k]| and j < k)}
    // Ranks are a bijection -> each output slot written exactly once, no barriers.
    if (tid < NCOMP) {
        const float myv = a2s[tid];
        int rank = 0;
        #pragma unroll 8
        for (int j = 0; j < NCOMP; ++j) {
            const float vj = a2s[j];  // broadcast
            rank += (vj > myv || (vj == myv && j < tid)) ? 1 : 0;
        }
        if (rank < KOUT) {
            const float4 a = eA[tid];
            const float4 c = cC[tid];
            const float ww = w2s[tid];
            float* dst = out_sel + (size_t)((b*LO + lo)*KOUT + rank)*7;
            dst[0] = ww; dst[1] = a.y; dst[2] = a.z;
            dst[3] = c.x; dst[4] = c.y; dst[5] = c.z; dst[6] = c.w;
            const float det = c.x*c.w - c.y*c.z;
            selint[rank] = sane(fabsf(ww) * TWO_PI_F * sqrtf(fmaxf(det, EPS_F)));
        }
    }
    __syncthreads();
    if (tid == 0) {
        float s = 0.f;
        for (int i = 0; i < KOUT; ++i) s += selint[i];
        out_tot[b*LO + lo] = s;
    }
}

// Final: batchnorm3 scale (mean over batch) -> integrate -> log_softmax -> f32
__global__ __launch_bounds__(64) void final_kernel(
    const float* __restrict__ sel3,   // (B,10,5,7)
    const float* __restrict__ tot3,   // (B,10)
    float* __restrict__ out)          // (B,10) f32
{
    const int b = blockIdx.x;
    const int tid = threadIdx.x;
    __shared__ float scale3[10], integ[10], red2[2];
    if (tid < 10) {
        float s = 0.f;
        for (int bb = 0; bb < BATCH; ++bb) s += tot3[bb*10 + tid];
        scale3[tid] = 1.f / (s / (float)BATCH + EPS_F);
    }
    __syncthreads();
    if (tid < 10) {
        float s = 0.f;
        const float* base = sel3 + (size_t)((b*10 + tid)*5)*7;
        for (int kk = 0; kk < 5; ++kk) {
            const float* c = base + kk*7;
            const float det = c[3]*c[6] - c[4]*c[5];
            s += c[0] * scale3[tid] * TWO_PI_F * sqrtf(fmaxf(det, EPS_F));
        }
        integ[tid] = sane(s);
    }
    __syncthreads();
    if (tid == 0) {
        float m = -1e30f;
        for (int l = 0; l < 10; ++l) m = fmaxf(m, integ[l]);
        float ss = 0.f;
        for (int l = 0; l < 10; ++l) ss += __expf(integ[l] - m);
        red2[0] = m; red2[1] = logf(ss);
    }
    __syncthreads();
    if (tid < 10) out[b*10 + tid] = integ[tid] - red2[0] - red2[1];
}

extern "C" void kernel_launch(void* const* d_in, const int* in_sizes, int n_in,
                              void* d_out, int out_size, void* d_ws, size_t ws_size,
                              hipStream_t stream)
{
    const float* in_x = (const float*)d_in[0];
    const float* k1   = (const float*)d_in[1];
    const float* k2   = (const float*)d_in[2];
    const float* k3   = (const float*)d_in[3];
    const float* b1   = (const float*)d_in[4];
    const float* b2   = (const float*)d_in[5];
    const float* b3   = (const float*)d_in[6];
    float* out = (float*)d_out;   // reference output dtype is float32

    float* ws = (float*)d_ws;
    float* sel1 = ws;                  // 32*5*25*7  = 28000 floats
    float* tot1 = ws + 28000;          // 160
    float* sel2 = ws + 28160;          // 32*6*12*7  = 16128
    float* tot2 = ws + 44288;          // 192
    float* sel3 = ws + 44480;          // 32*10*5*7  = 11200
    float* tot3 = ws + 55680;          // 320  (total ~224 KB)

    // Layer 1: (32,1,64) conv (5,1,5) -> 320 comps, keep 25. KPAD=320, G=3.
    layer_kernel<5, 1, 64, 5, 320, 25, 320, 3, true><<<BATCH*5, NT, 0, stream>>>(
        in_x, nullptr, nullptr, k1, b1, sel1, tot1);
    // Layer 2: (32,5,25) conv (6,5,5) -> 625 comps, keep 12. KPAD=640, G=1.
    layer_kernel<6, 5, 25, 5, 625, 12, 640, 1, false><<<BATCH*6, NT, 0, stream>>>(
        nullptr, sel1, tot1, k2, b2, sel2, tot2);
    // Layer 3: (32,6,12) conv (10,6,5) -> 360 comps, keep 5. KPAD=384, G=2.
    layer_kernel<10, 6, 12, 5, 360, 5, 384, 2, false><<<BATCH*10, NT, 0, stream>>>(
        nullptr, sel2, tot2, k3, b3, sel3, tot3);
    // Final: batchnorm + integrate + log_softmax
    final_kernel<<<BATCH, 64, 0, stream>>>(sel3, tot3, out);
}

// Round 5
// 188.834 us; speedup vs baseline: 1.4357x; 1.1598x over previous
//
#include <hip/hip_runtime.h>

#define TWO_PI_F 6.283185307179586f
#define EPS_F 1e-6f
#define BATCH 32

// Replace non-finite by 0 (bit test so fast-math can't fold it away).
__device__ __forceinline__ float sane(float x) {
    return ((__float_as_uint(x) & 0x7f800000u) == 0x7f800000u) ? 0.f : x;
}

// One fused layer: [apply prev batchnorm] -> gm_convolve -> eval_at_centers ->
// relu_fit (top-KOUT via stable rank) -> write selected comps + abs-integral.
//
// Thread layout: NT = TPG*G threads; t -> (g = t/TPG, kt = t%TPG).
// Each active thread (kt < KUSE = NCOMP/KP) owns KP k-slots {kt + j*KUSE} held
// in registers; group g sums the n-slice [g*CHUNK, ...). This amortizes each
// per-n LDS broadcast (b128+b64, ~20 cyc on the CU's single LDS unit) over KP
// register-resident evals: LDS demand = NCOMP^2*20/(64*KP) cyc vs VALU floor
// NCOMP^2*20/256 — balanced at KP~5. Rank phase uses the same trick + float4
// a2s reads (4 candidates per ds_read_b128).
template<int LO, int LI, int ND, int NK, int NCOMP, int KOUT,
         int KP, int TPG, int G, bool FIRST>
__global__ __launch_bounds__(TPG*G) void layer_kernel(
    const float* __restrict__ in_x,            // FIRST: (B,1,64,7) f32
    const float* __restrict__ prev_sel,        // !FIRST: (B,LI,ND,7) f32
    const float* __restrict__ prev_tot,        // !FIRST: (B,LI) f32
    const float* __restrict__ kern,            // (LO,LI,NK,7) f32
    const float* __restrict__ bias,            // (LO,) f32
    float* __restrict__ out_sel,               // (B,LO,KOUT,7) f32
    float* __restrict__ out_tot)               // (B,LO) f32
{
    constexpr int KUSE   = NCOMP / KP;
    static_assert(KUSE * KP == NCOMP, "exact k tiling required");
    constexpr int NT     = TPG * G;
    constexpr int CHUNK  = (NCOMP + G - 1) / G;
    constexpr int NCOMP4 = (NCOMP + 3) & ~3;
    constexpr int NQ     = NCOMP4 / 4;
    constexpr int CQ     = (NQ + G - 1) / G;

    const int b   = blockIdx.x / LO;
    const int lo  = blockIdx.x % LO;
    const int tid = threadIdx.x;
    const int g   = tid / TPG;
    const int kt  = tid % TPG;
    const bool active = (kt < KUSE);

    __shared__ float  d_w[LI*ND], d_px[LI*ND], d_py[LI*ND];
    __shared__ float4 d_c[LI*ND];
    __shared__ float  k_w[LI*NK], k_px[LI*NK], k_py[LI*NK];
    __shared__ float4 k_c[LI*NK];
    __shared__ float4 eA[NCOMP];   // w, px, py, -0.5*i00
    __shared__ float2 eB[NCOMP];   // -0.5*(i01+i10), -0.5*i11
    __shared__ float4 cC[NCOMP];   // C00,C01,C10,C11
    __shared__ float  w2s[NCOMP];
    __shared__ __align__(16) float a2s[NCOMP4];
    __shared__ float  accbuf[G*TPG*KP];   // eval partials, then rank partials
    __shared__ float  scr[64];
    __shared__ float  selint[32];
    __shared__ float  dscale[LI];

    // ---- Phase pre: incoming batchnorm + stage data/kernel into LDS
    if constexpr (FIRST) {
        // per_gaussian=True batchnorm on raw input (LI==1, ND==64)
        if (tid < ND) {
            const float* s = in_x + (size_t)(b*ND + tid)*7;
            const float w  = sane(s[0]);
            const float c0 = sane(s[3]), c1 = sane(s[4]), c2 = sane(s[5]), c3 = sane(s[6]);
            d_w[tid] = w; d_px[tid] = sane(s[1]); d_py[tid] = sane(s[2]);
            d_c[tid] = make_float4(c0, c1, c2, c3);
            const float det = c0*c3 - c1*c2;
            scr[tid] = sane(fabsf(w) * TWO_PI_F * sqrtf(fmaxf(det, EPS_F)));
        }
        __syncthreads();
        if (tid == 0) {
            float s = 0.f;
            for (int i = 0; i < ND; ++i) s += scr[i];
            dscale[0] = 1.f / (s + EPS_F);
        }
        __syncthreads();
        if (tid < ND) d_w[tid] = sane(d_w[tid] * dscale[0]);
    } else {
        // per_gaussian=False batchnorm: per input channel li, mean over batch
        if (tid < LI) {
            float s = 0.f;
            for (int bb = 0; bb < BATCH; ++bb) s += prev_tot[bb*LI + tid];
            dscale[tid] = 1.f / (s / (float)BATCH + EPS_F);
        }
        __syncthreads();
        if (tid < LI*ND) {
            const int li = tid / ND;
            const float* s = prev_sel + (size_t)(b*LI*ND + tid)*7;
            d_w[tid]  = sane(s[0] * dscale[li]);
            d_px[tid] = s[1]; d_py[tid] = s[2];
            d_c[tid]  = make_float4(s[3], s[4], s[5], s[6]);
        }
    }
    if (tid < LI*NK) {
        const float* s = kern + (size_t)(lo*LI*NK + tid)*7;
        k_w[tid]  = sane(s[0]);
        k_px[tid] = sane(s[1]); k_py[tid] = sane(s[2]);
        k_c[tid]  = make_float4(sane(s[3]), sane(s[4]), sane(s[5]), sane(s[6]));
    }
    __syncthreads();

    // ---- Phase A: gm_convolve -> NCOMP components in LDS
    // Flattening matches reference reshape: (li, nd, nk), nk fastest.
    if (tid < NCOMP) {
        const int li = tid / (ND*NK);
        const int r  = tid % (ND*NK);
        const int nd = r / NK, nk = r % NK;
        const int di = li*ND + nd, ki = li*NK + nk;
        const float4 dc = d_c[di], kc = k_c[ki];
        const float c0 = dc.x + kc.x, c1 = dc.y + kc.y, c2 = dc.z + kc.z, c3 = dc.w + kc.w;
        const float dd = dc.x*dc.w - dc.y*dc.z;
        const float dk = kc.x*kc.w - kc.y*kc.z;
        const float ds = c0*c3 - c1*c2;
        const float w  = sane(d_w[di]*k_w[ki]*TWO_PI_F*sqrtf(fmaxf(dd*dk, 0.f) / fmaxf(ds, EPS_F)));
        const float px = sane(d_px[di] + k_px[ki]);
        const float py = sane(d_py[di] + k_py[ki]);
        const float inv = 1.f / ds;   // reference inv2 uses the raw determinant
        const float i00 = sane(c3*inv), i01s = sane(-(c1 + c2)*inv), i11 = sane(c0*inv);
        eA[tid] = make_float4(w, px, py, -0.5f*i00);
        eB[tid] = make_float2(-0.5f*i01s, -0.5f*i11);
        cC[tid] = make_float4(sane(c0), sane(c1), sane(c2), sane(c3));
    }
    __syncthreads();

    // ---- Phase B: eval_at_centers, KP k-slots per thread, n split across G
    float kx[KP], ky[KP], acc[KP];
    #pragma unroll
    for (int j = 0; j < KP; ++j) {
        acc[j] = 0.f; kx[j] = 0.f; ky[j] = 0.f;
        if (active) { const float4 a = eA[kt + j*KUSE]; kx[j] = a.y; ky[j] = a.z; }
    }
    {
        const int n0 = g*CHUNK;
        const int n1 = (n0 + CHUNK < NCOMP) ? (n0 + CHUNK) : NCOMP;
        #pragma unroll 2
        for (int n = n0; n < n1; ++n) {
            const float4 a = eA[n];   // wave-broadcast (same n across lanes)
            const float2 e = eB[n];
            #pragma unroll
            for (int j = 0; j < KP; ++j) {
                const float dx = kx[j] - a.y;
                const float dy = ky[j] - a.z;
                const float u  = a.w*dx + e.x*dy;
                const float md = fminf(dx*u + (e.y*dy)*dy, 0.f);
                acc[j] += a.x * __expf(md);
            }
        }
    }
    if (g > 0 && active) {
        #pragma unroll
        for (int j = 0; j < KP; ++j) accbuf[(g*TPG + kt)*KP + j] = acc[j];
    }
    __syncthreads();

    const float bi = bias[lo];
    if (g == 0 && active) {
        #pragma unroll
        for (int j = 0; j < KP; ++j) {
            float s = acc[j];
            for (int gg = 1; gg < G; ++gg) s += accbuf[(gg*TPG + kt)*KP + j];
            const float v  = s + bi;
            const float sc = fmaxf(v, 0.f) / (fabsf(v) + EPS_F);
            const int   k  = kt + j*KUSE;
            const float ww = sane(eA[k].x * sc);
            w2s[k] = ww;
            a2s[k] = fabsf(ww);
        }
    }
    if constexpr (NCOMP4 > NCOMP) {
        if (tid >= NCOMP && tid < NCOMP4) a2s[tid] = -1.f;  // pad: never ranks
    }
    __syncthreads();

    // ---- Phase C: stable-descending rank (== jax.lax.top_k order), group-split
    // rank(k) = #{j : a2s[j] > a2s[k]  or  (a2s[j] == a2s[k] and j < k)}
    int rank[KP];
    float myv[KP];
    #pragma unroll
    for (int j = 0; j < KP; ++j) rank[j] = 0;
    if (active) {
        #pragma unroll
        for (int j = 0; j < KP; ++j) myv[j] = a2s[kt + j*KUSE];
        const int q0 = g*CQ;
        const int q1 = (q0 + CQ < NQ) ? (q0 + CQ) : NQ;
        for (int q = q0; q < q1; ++q) {
            const float4 v4 = ((const float4*)a2s)[q];  // broadcast
            #pragma unroll
            for (int c = 0; c < 4; ++c) {
                const float vj = (c == 0) ? v4.x : (c == 1) ? v4.y : (c == 2) ? v4.z : v4.w;
                const int   jj = 4*q + c;
                #pragma unroll
                for (int j = 0; j < KP; ++j) {
                    const int myk = kt + j*KUSE;
                    rank[j] += (vj > myv[j] || (vj == myv[j] && jj < myk)) ? 1 : 0;
                }
            }
        }
        if (g > 0) {
            #pragma unroll
            for (int j = 0; j < KP; ++j) accbuf[(g*TPG + kt)*KP + j] = (float)rank[j];
        }
    }
    __syncthreads();

    // ---- Phase D: g==0 finalizes ranks, writes selected comps + integrals
    if (g == 0 && active) {
        #pragma unroll
        for (int j = 0; j < KP; ++j) {
            int r = rank[j];
            for (int gg = 1; gg < G; ++gg) r += (int)accbuf[(gg*TPG + kt)*KP + j];
            if (r < KOUT) {
                const int k = kt + j*KUSE;
                const float4 a = eA[k];
                const float4 c = cC[k];
                const float ww = w2s[k];
                float* dst = out_sel + (size_t)((b*LO + lo)*KOUT + r)*7;
                dst[0] = ww; dst[1] = a.y; dst[2] = a.z;
                dst[3] = c.x; dst[4] = c.y; dst[5] = c.z; dst[6] = c.w;
                const float det = c.x*c.w - c.y*c.z;
                selint[r] = sane(fabsf(ww) * TWO_PI_F * sqrtf(fmaxf(det, EPS_F)));
            }
        }
    }
    __syncthreads();
    if (tid == 0) {
        float s = 0.f;
        for (int i = 0; i < KOUT; ++i) s += selint[i];
        out_tot[b*LO + lo] = s;
    }
}

// Final: batchnorm3 scale (mean over batch) -> integrate -> log_softmax -> f32
__global__ __launch_bounds__(64) void final_kernel(
    const float* __restrict__ sel3,   // (B,10,5,7)
    const float* __restrict__ tot3,   // (B,10)
    float* __restrict__ out)          // (B,10) f32
{
    const int b = blockIdx.x;
    const int tid = threadIdx.x;
    __shared__ float scale3[10], integ[10], red2[2];
    if (tid < 10) {
        float s = 0.f;
        for (int bb = 0; bb < BATCH; ++bb) s += tot3[bb*10 + tid];
        scale3[tid] = 1.f / (s / (float)BATCH + EPS_F);
    }
    __syncthreads();
    if (tid < 10) {
        float s = 0.f;
        const float* base = sel3 + (size_t)((b*10 + tid)*5)*7;
        for (int kk = 0; kk < 5; ++kk) {
            const float* c = base + kk*7;
            const float det = c[3]*c[6] - c[4]*c[5];
            s += c[0] * scale3[tid] * TWO_PI_F * sqrtf(fmaxf(det, EPS_F));
        }
        integ[tid] = sane(s);
    }
    __syncthreads();
    if (tid == 0) {
        float m = -1e30f;
        for (int l = 0; l < 10; ++l) m = fmaxf(m, integ[l]);
        float ss = 0.f;
        for (int l = 0; l < 10; ++l) ss += __expf(integ[l] - m);
        red2[0] = m; red2[1] = logf(ss);
    }
    __syncthreads();
    if (tid < 10) out[b*10 + tid] = integ[tid] - red2[0] - red2[1];
}

extern "C" void kernel_launch(void* const* d_in, const int* in_sizes, int n_in,
                              void* d_out, int out_size, void* d_ws, size_t ws_size,
                              hipStream_t stream)
{
    const float* in_x = (const float*)d_in[0];
    const float* k1   = (const float*)d_in[1];
    const float* k2   = (const float*)d_in[2];
    const float* k3   = (const float*)d_in[3];
    const float* b1   = (const float*)d_in[4];
    const float* b2   = (const float*)d_in[5];
    const float* b3   = (const float*)d_in[6];
    float* out = (float*)d_out;   // reference output dtype is float32

    float* ws = (float*)d_ws;
    float* sel1 = ws;                  // 32*5*25*7  = 28000 floats
    float* tot1 = ws + 28000;          // 160
    float* sel2 = ws + 28160;          // 32*6*12*7  = 16128
    float* tot2 = ws + 44288;          // 192
    float* sel3 = ws + 44480;          // 32*10*5*7  = 11200
    float* tot3 = ws + 55680;          // 320  (total ~224 KB)

    // Layer 1: 320 comps, keep 25.  KP=5 (64*5=320), TPG=64, G=16 -> NT=1024.
    layer_kernel<5, 1, 64, 5, 320, 25, 5, 64, 16, true><<<BATCH*5, 1024, 0, stream>>>(
        in_x, nullptr, nullptr, k1, b1, sel1, tot1);
    // Layer 2: 625 comps, keep 12.  KP=5 (125*5=625), TPG=128, G=8 -> NT=1024.
    layer_kernel<6, 5, 25, 5, 625, 12, 5, 128, 8, false><<<BATCH*6, 1024, 0, stream>>>(
        nullptr, sel1, tot1, k2, b2, sel2, tot2);
    // Layer 3: 360 comps, keep 5.   KP=6 (60*6=360), TPG=64, G=6 -> NT=384
    //          (384-thread blocks: 320 blocks co-schedule ~2/CU).
    layer_kernel<10, 6, 12, 5, 360, 5, 6, 64, 6, false><<<BATCH*10, 384, 0, stream>>>(
        nullptr, sel2, tot2, k3, b3, sel3, tot3);
    // Final: batchnorm + integrate + log_softmax
    final_kernel<<<BATCH, 64, 0, stream>>>(sel3, tot3, out);
}